// Round 4
// baseline (7339.780 us; speedup 1.0000x reference)
//
#include <hip/hip_runtime.h>
#include <cstdint>
#include <cstddef>

#define ND 256          // embedding dim
#define NK 4096         // num codes
#define NROWS 65536     // 32*2048
#define M_OUT 16777216  // NROWS*ND
#define IDX_OFF (M_OUT + 4)

// ---------------- workspace layout (bytes) ----------------
#define WS_INV64   0                        // double[65536]  512KB
#define WS_E2_32   (512*1024)               // float[4096]    16KB
#define WS_E2_64   (WS_E2_32 + 16*1024)     // double[4096]   32KB
#define WS_EHI     (WS_E2_64 + 32*1024)     // ushort[1M]     2MB
#define WS_ELO     (WS_EHI + 2*1024*1024)   // ushort[1M]     2MB
#define WS_BESTIDX (WS_ELO + 2*1024*1024)   // int[65536]     256KB
#define WS_COUNTS  (WS_BESTIDX + 256*1024)  // int[4096]      16KB
#define WS_RCOUNT  (WS_COUNTS + 16*1024)    // int[1] + pad   16B
#define WS_RROWS   (WS_RCOUNT + 16)         // int[65536]     256KB
#define WS_PART    (WS_RROWS + 256*1024)    // double[16384]  128KB

typedef __attribute__((ext_vector_type(8))) short bf16x8;
typedef __attribute__((ext_vector_type(4))) float f32x4;

__device__ __forceinline__ unsigned short f2bf(float f) {
  union { float f; unsigned int u; } c; c.f = f;
  unsigned int u = c.u + 0x7fffu + ((c.u >> 16) & 1u);  // RNE
  return (unsigned short)(u >> 16);
}
__device__ __forceinline__ float bf2f(unsigned short h) {
  union { unsigned int u; float f; } c; c.u = ((unsigned int)h) << 16;
  return c.f;
}
// async 16B global->LDS DMA; LDS dest must be wave-uniform base + lane*16
__device__ __forceinline__ void gll16(const unsigned short* g, unsigned short* l) {
  __builtin_amdgcn_global_load_lds(
      (const __attribute__((address_space(1))) unsigned int*)g,
      (__attribute__((address_space(3))) unsigned int*)l, 16, 0, 0);
}

// ---------------- kernel 1: row norms + normalized bf16 hi/lo planes ----------------
__global__ void rownorm_k(const float* __restrict__ z, double* __restrict__ inv64,
                          unsigned short* __restrict__ zhi, unsigned short* __restrict__ zlo) {
  const int w = threadIdx.x >> 6, lane = threadIdx.x & 63;
  const int row = blockIdx.x * 4 + w;
  const float4 v = *reinterpret_cast<const float4*>(z + (size_t)row * ND + lane * 4);
  double s = (double)v.x * v.x + (double)v.y * v.y + (double)v.z * v.z + (double)v.w * v.w;
  #pragma unroll
  for (int m = 32; m; m >>= 1) s += __shfl_xor(s, m, 64);
  double nrm = sqrt(s);
  if (nrm < 1e-12) nrm = 1e-12;
  const double inv = 1.0 / nrm;
  if (lane == 0) inv64[row] = inv;
  float nv[4] = {(float)(v.x * inv), (float)(v.y * inv), (float)(v.z * inv), (float)(v.w * inv)};
  ushort4 h, lo;
  h.x = f2bf(nv[0]); h.y = f2bf(nv[1]); h.z = f2bf(nv[2]); h.w = f2bf(nv[3]);
  lo.x = f2bf(nv[0] - bf2f(h.x)); lo.y = f2bf(nv[1] - bf2f(h.y));
  lo.z = f2bf(nv[2] - bf2f(h.z)); lo.w = f2bf(nv[3] - bf2f(h.w));
  *reinterpret_cast<ushort4*>(zhi + (size_t)row * ND + lane * 4) = h;
  *reinterpret_cast<ushort4*>(zlo + (size_t)row * ND + lane * 4) = lo;
}

// ---------------- kernel 2: code norms + bf16 hi/lo planes ----------------
__global__ void embnorm_k(const float* __restrict__ e, float* __restrict__ e2_32,
                          double* __restrict__ e2_64, unsigned short* __restrict__ ehi,
                          unsigned short* __restrict__ elo) {
  const int w = threadIdx.x >> 6, lane = threadIdx.x & 63;
  const int row = blockIdx.x * 4 + w;
  const float4 v = *reinterpret_cast<const float4*>(e + (size_t)row * ND + lane * 4);
  double s = (double)v.x * v.x + (double)v.y * v.y + (double)v.z * v.z + (double)v.w * v.w;
  #pragma unroll
  for (int m = 32; m; m >>= 1) s += __shfl_xor(s, m, 64);
  if (lane == 0) { e2_64[row] = s; e2_32[row] = (float)s; }
  ushort4 h, lo;
  h.x = f2bf(v.x); h.y = f2bf(v.y); h.z = f2bf(v.z); h.w = f2bf(v.w);
  lo.x = f2bf(v.x - bf2f(h.x)); lo.y = f2bf(v.y - bf2f(h.y));
  lo.z = f2bf(v.z - bf2f(h.z)); lo.w = f2bf(v.w - bf2f(h.w));
  *reinterpret_cast<ushort4*>(ehi + (size_t)row * ND + lane * 4) = h;
  *reinterpret_cast<ushort4*>(elo + (size_t)row * ND + lane * 4) = lo;
}

// ---------------- kernel 3: A-persistent split-bf16 MFMA GEMM + argmin ----------------
// MB=64 rows/block: rows 0..31 in LDS (full K, both planes, 32 KB, loaded once);
// rows 32..63 as persistent register fragments (64 VGPR, loaded once).
// B streams in 16 KB chunks (64 codes x 64 k x hi/lo), double-buffered:
// stage(c+1) -> compute(c) -> barrier, so the vmcnt drain lands after compute.
// LDS 64 KB total -> 2 blocks/CU. acc = Ah*Bh + Ah*Bl + Al*Bh (err ~4e-5 worst).
#define MARGIN 1.5e-4f

__launch_bounds__(256, 2)
__global__ void phase1_k(const unsigned short* __restrict__ zhi, const unsigned short* __restrict__ zlo,
                         const unsigned short* __restrict__ ehi, const unsigned short* __restrict__ elo,
                         const float* __restrict__ e2,
                         int* __restrict__ best_idx, int* __restrict__ rcount,
                         int* __restrict__ rrows) {
  __shared__ __align__(16) unsigned short smem[32768];  // 64 KB
  // layout (ushorts): Ah[32][256] @0, Al @8192, buf0 {Bh[64][64]@16384, Bl@20480}, buf1 @24576
  const int t = threadIdx.x;
  const int l = t & 63;
  const int wave = t >> 6;              // 0..3
  const int l15 = l & 15, l4 = l >> 4;
  const int wm = wave & 1, wq = wave >> 1;
  const int row0 = blockIdx.x * 64;

  // ---- stage A rows 0..31 (both planes) into LDS, once; XOR-seg swizzle ----
  {
    const unsigned short* src = (wave >> 1) ? zlo : zhi;  // waves 0,1 -> hi; 2,3 -> lo
    #pragma unroll
    for (int j = 0; j < 8; ++j) {
      const int op = (wave & 1) * 8192 + j * 1024 + l * 16;  // within-plane byte
      const int row = op >> 9;                               // 0..31
      const int segl = (l & 31) ^ (row & 7);
      gll16(src + (size_t)(row0 + row) * ND + segl * 8,
            smem + wave * 4096 + j * 512 + l * 8);
    }
  }
  // ---- A rows 32..63: persistent register fragments ----
  bf16x8 aRH[8], aRL[8];
  {
    const size_t rbase = (size_t)(row0 + 32 + wm * 16 + l15) * ND + l4 * 8;
    #pragma unroll
    for (int k = 0; k < 8; ++k) {
      aRH[k] = *reinterpret_cast<const bf16x8*>(zhi + rbase + (size_t)k * 32);
      aRL[k] = *reinterpret_cast<const bf16x8*>(zlo + rbase + (size_t)k * 32);
    }
  }
  // ---- B staging invariants (4 gll16 per lane per chunk) ----
  const unsigned short* bsrc = (wave >> 1) ? elo : ehi;
  size_t boffs[4];
  int bdst[4];
  #pragma unroll
  for (int jj = 0; jj < 4; ++jj) {
    const int o = wave * 4096 + jj * 1024 + l * 16;  // byte within 16 KB chunk
    const int op = o & 8191;                         // within-plane
    const int code = op >> 7;                        // 0..63
    const int segl = (l & 7) ^ (code & 7);
    boffs[jj] = (size_t)code * ND + segl * 8;
    bdst[jj] = 16384 + o / 2;                        // ushort idx in buf0
  }
  // prologue: stage chunk 0 into buf0
  #pragma unroll
  for (int jj = 0; jj < 4; ++jj) gll16(bsrc + boffs[jj], smem + bdst[jj]);

  // compute-side invariants
  const int arow = wm * 16 + l15;       // LDS A row (mt0)
  const int aidx0 = arow * 256;
  const int asw = (arow & 7) * 8;
  int brow[2], bsw[2];
  #pragma unroll
  for (int nt = 0; nt < 2; ++nt) {
    brow[nt] = wq * 32 + nt * 16 + l15;
    bsw[nt] = (brow[nt] & 7) * 8;
  }

  float b1[8], b2[8]; int i1[8];
  #pragma unroll
  for (int s = 0; s < 8; ++s) { b1[s] = 3.4e38f; b2[s] = 3.4e38f; i1[s] = 0; }

  f32x4 acc[2][2];
  __syncthreads();

  for (int c = 0; c < 256; ++c) {       // chunk = (ct = c>>2, ks = c&3)
    const int p = c & 1;
    if (c < 255) {                      // prefetch next chunk into other buffer
      const int cn = c + 1;
      const size_t off = (size_t)((cn >> 2) * 64) * ND + (size_t)((cn & 3) * 64);
      const int dsh = ((cn & 1) ^ 0) * 8192;  // buf parity offset (ushorts)
      #pragma unroll
      for (int jj = 0; jj < 4; ++jj)
        gll16(bsrc + off + boffs[jj], smem + bdst[jj] + ((cn & 1) * 8192));
      (void)dsh;
    }
    if ((c & 3) == 0) {
      #pragma unroll
      for (int mt = 0; mt < 2; ++mt)
        #pragma unroll
        for (int nt = 0; nt < 2; ++nt) acc[mt][nt] = (f32x4){0.f, 0.f, 0.f, 0.f};
    }
    const int bb = 16384 + p * 8192;
    const int ksu = (c & 3) * 64;
    #pragma unroll
    for (int kk = 0; kk < 2; ++kk) {
      const int ko = kk * 32 + l4 * 8;
      const int ai = aidx0 + ((ksu + ko) ^ asw);
      const bf16x8 a0H = *reinterpret_cast<const bf16x8*>(&smem[ai]);
      const bf16x8 a0L = *reinterpret_cast<const bf16x8*>(&smem[8192 + ai]);
      bf16x8 bH[2], bL[2];
      #pragma unroll
      for (int nt = 0; nt < 2; ++nt) {
        const int bi = bb + brow[nt] * 64 + (ko ^ bsw[nt]);
        bH[nt] = *reinterpret_cast<const bf16x8*>(&smem[bi]);
        bL[nt] = *reinterpret_cast<const bf16x8*>(&smem[bi + 4096]);
      }
      const int kidx = (c & 3) * 2 + kk;
      #pragma unroll
      for (int nt = 0; nt < 2; ++nt) {
        acc[0][nt] = __builtin_amdgcn_mfma_f32_16x16x32_bf16(a0H, bH[nt], acc[0][nt], 0, 0, 0);
        acc[0][nt] = __builtin_amdgcn_mfma_f32_16x16x32_bf16(a0H, bL[nt], acc[0][nt], 0, 0, 0);
        acc[0][nt] = __builtin_amdgcn_mfma_f32_16x16x32_bf16(a0L, bH[nt], acc[0][nt], 0, 0, 0);
        acc[1][nt] = __builtin_amdgcn_mfma_f32_16x16x32_bf16(aRH[kidx], bH[nt], acc[1][nt], 0, 0, 0);
        acc[1][nt] = __builtin_amdgcn_mfma_f32_16x16x32_bf16(aRH[kidx], bL[nt], acc[1][nt], 0, 0, 0);
        acc[1][nt] = __builtin_amdgcn_mfma_f32_16x16x32_bf16(aRL[kidx], bH[nt], acc[1][nt], 0, 0, 0);
      }
    }
    if ((c & 3) == 3) {                 // epilogue for ct = c>>2 (regs + e2 only)
      const int ct = c >> 2;
      #pragma unroll
      for (int nt = 0; nt < 2; ++nt) {
        const int code = ct * 64 + wq * 32 + nt * 16 + l15;
        const float e2c = e2[code];
        #pragma unroll
        for (int mt = 0; mt < 2; ++mt)
          #pragma unroll
          for (int r = 0; r < 4; ++r) {
            const float sv = fmaf(-2.0f, acc[mt][nt][r], e2c);
            const int s = mt * 4 + r;
            if (sv < b1[s]) { b2[s] = b1[s]; b1[s] = sv; i1[s] = code; }
            else if (sv < b2[s]) b2[s] = sv;
          }
      }
    }
    __syncthreads();
  }

  // butterfly merge across the 16 lanes (l15) sharing each row
  #pragma unroll
  for (int s = 0; s < 8; ++s) {
    #pragma unroll
    for (int m = 1; m < 16; m <<= 1) {
      const float ob1 = __shfl_xor(b1[s], m, 64);
      const float ob2 = __shfl_xor(b2[s], m, 64);
      const int oi1 = __shfl_xor(i1[s], m, 64);
      if (ob1 < b1[s] || (ob1 == b1[s] && oi1 < i1[s])) {
        b2[s] = fminf(b1[s], ob2); b1[s] = ob1; i1[s] = oi1;
      } else b2[s] = fminf(b2[s], ob1);
    }
  }
  // cross-wave (wq=0/1) merge via small LDS
  float* M1 = (float*)smem;        // [64][2]
  float* M2 = M1 + 128;
  int*   MI = (int*)(M2 + 128);
  if (l15 == 0) {
    #pragma unroll
    for (int s = 0; s < 8; ++s) {
      const int mt = s >> 2, r = s & 3;
      const int row = mt * 32 + wm * 16 + l4 * 4 + r;
      M1[row * 2 + wq] = b1[s];
      M2[row * 2 + wq] = b2[s];
      MI[row * 2 + wq] = i1[s];
    }
  }
  __syncthreads();
  if (t < 64) {
    float B1 = M1[t * 2], B2v = M2[t * 2];
    int I1 = MI[t * 2];
    const float y1 = M1[t * 2 + 1], y2 = M2[t * 2 + 1];
    const int yi = MI[t * 2 + 1];
    if (y1 < B1 || (y1 == B1 && yi < I1)) { B2v = fminf(B1, y2); B1 = y1; I1 = yi; }
    else B2v = fminf(B2v, y1);
    const int row = row0 + t;
    best_idx[row] = I1;
    if (B2v - B1 < MARGIN) {
      const int pos = atomicAdd(rcount, 1);
      rrows[pos] = row;
    }
  }
}

// ---------------- kernel 4: exact fp64 recheck, coalesced (wave-per-code) ----------------
__global__ void phase2_k(const float* __restrict__ z, const float* __restrict__ emb,
                         const double* __restrict__ e2_64, const double* __restrict__ inv64,
                         const int* __restrict__ rcount, const int* __restrict__ rrows,
                         int* __restrict__ best_idx) {
  __shared__ double zn[ND];
  __shared__ double RB[4];
  __shared__ int RI[4];
  const int t = threadIdx.x;
  const int w = t >> 6, l = t & 63;
  int cnt = rcount[0];
  if (cnt > NROWS) cnt = NROWS;
  for (int e = blockIdx.x; e < cnt; e += gridDim.x) {
    const int row = rrows[e];
    __syncthreads();
    zn[t] = (double)z[(size_t)row * ND + t] * inv64[row];
    __syncthreads();
    const double z0 = zn[l * 4], z1 = zn[l * 4 + 1], z2 = zn[l * 4 + 2], z3 = zn[l * 4 + 3];
    double B1 = 1e300;
    int I1 = 0;
    for (int c = w; c < NK; c += 4) {   // ascending per wave -> lowest-index tie within wave
      const float4 ev = *reinterpret_cast<const float4*>(emb + (size_t)c * ND + l * 4);
      double d = z0 * ev.x + z1 * ev.y + z2 * ev.z + z3 * ev.w;
      #pragma unroll
      for (int m = 32; m; m >>= 1) d += __shfl_xor(d, m, 64);
      const double s = e2_64[c] - 2.0 * d;
      if (s < B1) { B1 = s; I1 = c; }
    }
    if (l == 0) { RB[w] = B1; RI[w] = I1; }
    __syncthreads();
    if (t == 0) {
      double bb = RB[0]; int bi = RI[0];
      #pragma unroll
      for (int k = 1; k < 4; ++k)
        if (RB[k] < bb || (RB[k] == bb && RI[k] < bi)) { bb = RB[k]; bi = RI[k]; }
      best_idx[row] = bi;
    }
  }
}

// ---------------- kernel 5: gather z_q, loss partials, histogram, index output ----------------
__global__ void gather_k(const float* __restrict__ z, const float* __restrict__ emb,
                         const int* __restrict__ best_idx, const double* __restrict__ inv64,
                         float* __restrict__ out, double* __restrict__ partials,
                         int* __restrict__ counts) {
  __shared__ double wsum[4];
  const int w = threadIdx.x >> 6, lane = threadIdx.x & 63;
  const int row = blockIdx.x * 4 + w;
  const int idx = best_idx[row];
  const double inv = inv64[row];
  const float4 zv = *reinterpret_cast<const float4*>(z + (size_t)row * ND + lane * 4);
  const float4 ev = *reinterpret_cast<const float4*>(emb + (size_t)idx * ND + lane * 4);
  *reinterpret_cast<float4*>(out + (size_t)row * ND + lane * 4) = ev;  // z_q_st == z_q
  const double dx = (double)ev.x - (double)zv.x * inv;
  const double dy = (double)ev.y - (double)zv.y * inv;
  const double dz = (double)ev.z - (double)zv.z * inv;
  const double dw = (double)ev.w - (double)zv.w * inv;
  double s = dx * dx + dy * dy + dz * dz + dw * dw;
  #pragma unroll
  for (int m = 32; m; m >>= 1) s += __shfl_xor(s, m, 64);
  if (lane == 0) {
    wsum[w] = s;
    atomicAdd(&counts[idx], 1);
    out[IDX_OFF + row] = (float)idx;
  }
  __syncthreads();
  if (threadIdx.x == 0) partials[blockIdx.x] = wsum[0] + wsum[1] + wsum[2] + wsum[3];
}

// ---------------- kernel 6: scalars (losses + perplexity) ----------------
__global__ void finalize_k(const double* __restrict__ partials, const int* __restrict__ counts,
                           float* __restrict__ out) {
  __shared__ double red[256];
  const int t = threadIdx.x;
  double s = 0.0;
  for (int k = 0; k < 64; ++k) s += partials[t + 256 * k];
  red[t] = s;
  __syncthreads();
  for (int off = 128; off; off >>= 1) {
    if (t < off) red[t] += red[t + off];
    __syncthreads();
  }
  const double c = red[0] / (double)M_OUT;  // codebook_loss == commitment_loss
  __syncthreads();
  double h = 0.0;
  for (int k = 0; k < 16; ++k) {
    const double p = (double)counts[t * 16 + k] * (1.0 / 65536.0);
    h += p * log(p + 1e-10);
  }
  red[t] = h;
  __syncthreads();
  for (int off = 128; off; off >>= 1) {
    if (t < off) red[t] += red[t + off];
    __syncthreads();
  }
  if (t == 0) {
    const double perp = exp(-red[0]);
    out[M_OUT + 0] = (float)(c + 0.25 * c);  // vq_loss
    out[M_OUT + 1] = (float)c;               // codebook_loss
    out[M_OUT + 2] = (float)c;               // commitment_loss
    out[M_OUT + 3] = (float)perp;            // perplexity
  }
}

extern "C" void kernel_launch(void* const* d_in, const int* in_sizes, int n_in,
                              void* d_out, int out_size, void* d_ws, size_t ws_size,
                              hipStream_t stream) {
  const float* z = (const float*)d_in[0];
  const float* emb = (const float*)d_in[1];
  float* out = (float*)d_out;
  char* ws = (char*)d_ws;
  double* inv64   = (double*)(ws + WS_INV64);
  float*  e2_32   = (float*)(ws + WS_E2_32);
  double* e2_64   = (double*)(ws + WS_E2_64);
  unsigned short* ehi = (unsigned short*)(ws + WS_EHI);
  unsigned short* elo = (unsigned short*)(ws + WS_ELO);
  int*    best_i  = (int*)(ws + WS_BESTIDX);
  int*    counts  = (int*)(ws + WS_COUNTS);
  int*    rcount  = (int*)(ws + WS_RCOUNT);
  int*    rrows   = (int*)(ws + WS_RROWS);
  double* partials = (double*)(ws + WS_PART);
  // z hi/lo planes live in d_out[0..16M floats) -- fully overwritten by gather_k later
  unsigned short* zhi = (unsigned short*)d_out;  // [65536][256]
  unsigned short* zlo = zhi + M_OUT;             // [65536][256]

  hipMemsetAsync(ws + WS_COUNTS, 0, 16 * 1024 + 16, stream);  // counts + rcount
  rownorm_k<<<NROWS / 4, 256, 0, stream>>>(z, inv64, zhi, zlo);
  embnorm_k<<<NK / 4, 256, 0, stream>>>(emb, e2_32, e2_64, ehi, elo);
  phase1_k<<<NROWS / 64, 256, 0, stream>>>(zhi, zlo, ehi, elo, e2_32, best_i, rcount, rrows);
  phase2_k<<<1024, 256, 0, stream>>>(z, emb, e2_64, inv64, rcount, rrows, best_i);
  gather_k<<<NROWS / 4, 256, 0, stream>>>(z, emb, best_i, inv64, out, partials, counts);
  finalize_k<<<1, 256, 0, stream>>>(partials, counts, out);
}

// Round 5
// 1135.121 us; speedup vs baseline: 6.4661x; 6.4661x over previous
//
#include <hip/hip_runtime.h>
#include <cstdint>
#include <cstddef>

#define ND 256          // embedding dim
#define NK 4096         // num codes
#define NROWS 65536     // 32*2048
#define M_OUT 16777216  // NROWS*ND
#define IDX_OFF (M_OUT + 4)

// ---------------- workspace layout (bytes) ----------------
#define WS_INV64   0                        // double[65536]  512KB
#define WS_E2_32   (512*1024)               // float[4096]    16KB
#define WS_E2_64   (WS_E2_32 + 16*1024)     // double[4096]   32KB
#define WS_EHI     (WS_E2_64 + 32*1024)     // ushort[1M]     2MB
#define WS_ELO     (WS_EHI + 2*1024*1024)   // ushort[1M]     2MB
#define WS_BESTIDX (WS_ELO + 2*1024*1024)   // int[65536]     256KB
#define WS_COUNTS  (WS_BESTIDX + 256*1024)  // int[4096]      16KB
#define WS_RCOUNT  (WS_COUNTS + 16*1024)    // int[1] + pad   16B
#define WS_RROWS   (WS_RCOUNT + 16)         // int[65536]     256KB
#define WS_PART    (WS_RROWS + 256*1024)    // double[16384]  128KB

typedef __attribute__((ext_vector_type(8))) short bf16x8;
typedef __attribute__((ext_vector_type(4))) float f32x4;

__device__ __forceinline__ unsigned short f2bf(float f) {
  union { float f; unsigned int u; } c; c.f = f;
  unsigned int u = c.u + 0x7fffu + ((c.u >> 16) & 1u);  // RNE
  return (unsigned short)(u >> 16);
}
__device__ __forceinline__ float bf2f(unsigned short h) {
  union { unsigned int u; float f; } c; c.u = ((unsigned int)h) << 16;
  return c.f;
}
// async 16B global->LDS DMA; dest = wave-uniform base + lane*16 (lane0's ptr is the base)
__device__ __forceinline__ void gll16(const unsigned short* g, unsigned short* l) {
  __builtin_amdgcn_global_load_lds(
      (const __attribute__((address_space(1))) unsigned int*)g,
      (__attribute__((address_space(3))) unsigned int*)l, 16, 0, 0);
}

// ---------------- kernel 1: row norms + normalized bf16 hi/lo planes ----------------
__global__ void rownorm_k(const float* __restrict__ z, double* __restrict__ inv64,
                          unsigned short* __restrict__ zhi, unsigned short* __restrict__ zlo) {
  const int w = threadIdx.x >> 6, lane = threadIdx.x & 63;
  const int row = blockIdx.x * 4 + w;
  const float4 v = *reinterpret_cast<const float4*>(z + (size_t)row * ND + lane * 4);
  double s = (double)v.x * v.x + (double)v.y * v.y + (double)v.z * v.z + (double)v.w * v.w;
  #pragma unroll
  for (int m = 32; m; m >>= 1) s += __shfl_xor(s, m, 64);
  double nrm = sqrt(s);
  if (nrm < 1e-12) nrm = 1e-12;
  const double inv = 1.0 / nrm;
  if (lane == 0) inv64[row] = inv;
  float nv[4] = {(float)(v.x * inv), (float)(v.y * inv), (float)(v.z * inv), (float)(v.w * inv)};
  ushort4 h, lo;
  h.x = f2bf(nv[0]); h.y = f2bf(nv[1]); h.z = f2bf(nv[2]); h.w = f2bf(nv[3]);
  lo.x = f2bf(nv[0] - bf2f(h.x)); lo.y = f2bf(nv[1] - bf2f(h.y));
  lo.z = f2bf(nv[2] - bf2f(h.z)); lo.w = f2bf(nv[3] - bf2f(h.w));
  *reinterpret_cast<ushort4*>(zhi + (size_t)row * ND + lane * 4) = h;
  *reinterpret_cast<ushort4*>(zlo + (size_t)row * ND + lane * 4) = lo;
}

// ---------------- kernel 2: code norms + bf16 hi/lo planes ----------------
__global__ void embnorm_k(const float* __restrict__ e, float* __restrict__ e2_32,
                          double* __restrict__ e2_64, unsigned short* __restrict__ ehi,
                          unsigned short* __restrict__ elo) {
  const int w = threadIdx.x >> 6, lane = threadIdx.x & 63;
  const int row = blockIdx.x * 4 + w;
  const float4 v = *reinterpret_cast<const float4*>(e + (size_t)row * ND + lane * 4);
  double s = (double)v.x * v.x + (double)v.y * v.y + (double)v.z * v.z + (double)v.w * v.w;
  #pragma unroll
  for (int m = 32; m; m >>= 1) s += __shfl_xor(s, m, 64);
  if (lane == 0) { e2_64[row] = s; e2_32[row] = (float)s; }
  ushort4 h, lo;
  h.x = f2bf(v.x); h.y = f2bf(v.y); h.z = f2bf(v.z); h.w = f2bf(v.w);
  lo.x = f2bf(v.x - bf2f(h.x)); lo.y = f2bf(v.y - bf2f(h.y));
  lo.z = f2bf(v.z - bf2f(h.z)); lo.w = f2bf(v.w - bf2f(h.w));
  *reinterpret_cast<ushort4*>(ehi + (size_t)row * ND + lane * 4) = h;
  *reinterpret_cast<ushort4*>(elo + (size_t)row * ND + lane * 4) = lo;
}

// ---------------- kernel 3: A-persistent split-bf16 MFMA GEMM + argmin ----------------
// 64 rows/block. Rows 0..31: LDS, full K, layout [ks:4][plane:2][row:32][64] (128 B row
// stride + XOR swizzle == R3's measured-zero-conflict pattern). Rows 32..63: persistent
// register fragments, ALL indices compile-time (ks,kk fully unrolled) -- no scratch.
// B streams 16 KB chunks (64 codes x 64 k x hi/lo), double-buffered, parity = ks&1.
#define MARGIN 1.5e-4f

__launch_bounds__(256, 2)
__global__ void phase1_k(const unsigned short* __restrict__ zhi, const unsigned short* __restrict__ zlo,
                         const unsigned short* __restrict__ ehi, const unsigned short* __restrict__ elo,
                         const float* __restrict__ e2,
                         int* __restrict__ best_idx, int* __restrict__ rcount,
                         int* __restrict__ rrows) {
  __shared__ __align__(16) unsigned short smem[32768];  // 64 KB
  // A: ushorts [0, 16384)  = [ks][plane][row][64]
  // B: ushorts [16384, 32768) = [par][plane][code][64]
  const int t = threadIdx.x;
  const int l = t & 63;
  const int wave = t >> 6;
  const int l15 = l & 15, l4 = l >> 4;
  const int wm = wave & 1, wq = wave >> 1;
  const int row0 = blockIdx.x * 64;

  // ---- stage A rows 0..31 into LDS once (wave w stages ks=w chunk: 8 KB) ----
  #pragma unroll
  for (int j = 0; j < 8; ++j) {
    const int o = wave * 8192 + j * 1024 + l * 16;       // global byte offset in A region
    const int p = (o >> 12) & 1;                         // plane within ks chunk
    const int row = (o >> 7) & 31;
    const int srcseg = ((o >> 4) & 7) ^ (row & 7);
    const unsigned short* src = p ? zlo : zhi;
    gll16(src + (size_t)(row0 + row) * ND + wave * 64 + srcseg * 8, smem + (o >> 1));
  }
  // ---- A rows 32..63: persistent register fragments (compile-time indexed) ----
  bf16x8 aRH[8], aRL[8];
  {
    const size_t rb = (size_t)(row0 + 32 + wm * 16 + l15) * ND + l4 * 8;
    #pragma unroll
    for (int k = 0; k < 8; ++k) {
      aRH[k] = *reinterpret_cast<const bf16x8*>(zhi + rb + (size_t)k * 32);
      aRL[k] = *reinterpret_cast<const bf16x8*>(zlo + rb + (size_t)k * 32);
    }
  }
  // ---- B staging invariants (4 gll16 per lane per 16 KB chunk) ----
  const unsigned short* bsrcP[4];
  size_t bco[4];
  int bdst[4];
  #pragma unroll
  for (int jj = 0; jj < 4; ++jj) {
    const int o = wave * 4096 + jj * 1024 + l * 16;      // byte offset within chunk
    const int plane = o >> 13;
    const int code = (o >> 7) & 63;
    const int srcseg = ((o >> 4) & 7) ^ (code & 7);
    bsrcP[jj] = plane ? elo : ehi;
    bco[jj] = (size_t)code * ND + srcseg * 8;
    bdst[jj] = 16384 + (o >> 1);
  }
  // prologue: stage chunk (ct=0, ks=0) into buf0
  #pragma unroll
  for (int jj = 0; jj < 4; ++jj) gll16(bsrcP[jj] + bco[jj], smem + bdst[jj]);

  // compute-side invariants
  const int aoff = (wm * 16 + l15) * 64;   // A row offset (within [plane] region)
  const int asw = (wm * 16 + l15) & 7;
  int boff[2], bsw[2];
  #pragma unroll
  for (int nt = 0; nt < 2; ++nt) {
    const int br = wq * 32 + nt * 16 + l15;
    boff[nt] = br * 64;
    bsw[nt] = br & 7;
  }

  float b1[8], b2[8]; int i1[8];
  #pragma unroll
  for (int s = 0; s < 8; ++s) { b1[s] = 3.4e38f; b2[s] = 3.4e38f; i1[s] = 0; }

  __syncthreads();

  for (int ct = 0; ct < 64; ++ct) {
    f32x4 acc[2][2];
    #pragma unroll
    for (int mt = 0; mt < 2; ++mt)
      #pragma unroll
      for (int nt = 0; nt < 2; ++nt) acc[mt][nt] = (f32x4){0.f, 0.f, 0.f, 0.f};

    #pragma unroll
    for (int ks = 0; ks < 4; ++ks) {
      // prefetch next chunk into buf[(ks+1)&1]
      if (ks < 3) {
        #pragma unroll
        for (int jj = 0; jj < 4; ++jj)
          gll16(bsrcP[jj] + (size_t)ct * 64 * ND + bco[jj] + (ks + 1) * 64,
                smem + bdst[jj] + ((ks + 1) & 1) * 8192);
      } else if (ct < 63) {
        #pragma unroll
        for (int jj = 0; jj < 4; ++jj)
          gll16(bsrcP[jj] + (size_t)(ct + 1) * 64 * ND + bco[jj],
                smem + bdst[jj]);                        // parity 0
      }
      const int Ab = ks * 4096;
      const int Bb = 16384 + (ks & 1) * 8192;
      #pragma unroll
      for (int kk = 0; kk < 2; ++kk) {
        const int sgA = ((kk * 4 + l4) ^ asw) * 8;
        const bf16x8 a0H = *reinterpret_cast<const bf16x8*>(&smem[Ab + aoff + sgA]);
        const bf16x8 a0L = *reinterpret_cast<const bf16x8*>(&smem[Ab + 2048 + aoff + sgA]);
        bf16x8 bH[2], bL[2];
        #pragma unroll
        for (int nt = 0; nt < 2; ++nt) {
          const int sgB = ((kk * 4 + l4) ^ bsw[nt]) * 8;
          bH[nt] = *reinterpret_cast<const bf16x8*>(&smem[Bb + boff[nt] + sgB]);
          bL[nt] = *reinterpret_cast<const bf16x8*>(&smem[Bb + 4096 + boff[nt] + sgB]);
        }
        #pragma unroll
        for (int nt = 0; nt < 2; ++nt) {
          acc[0][nt] = __builtin_amdgcn_mfma_f32_16x16x32_bf16(a0H, bH[nt], acc[0][nt], 0, 0, 0);
          acc[0][nt] = __builtin_amdgcn_mfma_f32_16x16x32_bf16(a0H, bL[nt], acc[0][nt], 0, 0, 0);
          acc[0][nt] = __builtin_amdgcn_mfma_f32_16x16x32_bf16(a0L, bH[nt], acc[0][nt], 0, 0, 0);
          acc[1][nt] = __builtin_amdgcn_mfma_f32_16x16x32_bf16(aRH[ks * 2 + kk], bH[nt], acc[1][nt], 0, 0, 0);
          acc[1][nt] = __builtin_amdgcn_mfma_f32_16x16x32_bf16(aRH[ks * 2 + kk], bL[nt], acc[1][nt], 0, 0, 0);
          acc[1][nt] = __builtin_amdgcn_mfma_f32_16x16x32_bf16(aRL[ks * 2 + kk], bH[nt], acc[1][nt], 0, 0, 0);
        }
      }
      __syncthreads();
    }
    // epilogue for this ct: score = e2 - 2*dot, running best/2nd (ascending code order)
    #pragma unroll
    for (int nt = 0; nt < 2; ++nt) {
      const int code = ct * 64 + wq * 32 + nt * 16 + l15;
      const float e2c = e2[code];
      #pragma unroll
      for (int mt = 0; mt < 2; ++mt)
        #pragma unroll
        for (int r = 0; r < 4; ++r) {
          const float sv = fmaf(-2.0f, acc[mt][nt][r], e2c);
          const int s = mt * 4 + r;
          if (sv < b1[s]) { b2[s] = b1[s]; b1[s] = sv; i1[s] = code; }
          else if (sv < b2[s]) b2[s] = sv;
        }
    }
  }

  // butterfly merge across the 16 lanes (l15) sharing each row
  #pragma unroll
  for (int s = 0; s < 8; ++s) {
    #pragma unroll
    for (int m = 1; m < 16; m <<= 1) {
      const float ob1 = __shfl_xor(b1[s], m, 64);
      const float ob2 = __shfl_xor(b2[s], m, 64);
      const int oi1 = __shfl_xor(i1[s], m, 64);
      if (ob1 < b1[s] || (ob1 == b1[s] && oi1 < i1[s])) {
        b2[s] = fminf(b1[s], ob2); b1[s] = ob1; i1[s] = oi1;
      } else b2[s] = fminf(b2[s], ob1);
    }
  }
  // cross-wave (wq=0/1) merge via small LDS
  __syncthreads();
  float* M1 = (float*)smem;        // [64][2]
  float* M2 = M1 + 128;
  int*   MI = (int*)(M2 + 128);
  if (l15 == 0) {
    #pragma unroll
    for (int s = 0; s < 8; ++s) {
      const int mt = s >> 2, r = s & 3;
      const int row = mt * 32 + wm * 16 + l4 * 4 + r;
      M1[row * 2 + wq] = b1[s];
      M2[row * 2 + wq] = b2[s];
      MI[row * 2 + wq] = i1[s];
    }
  }
  __syncthreads();
  if (t < 64) {
    float B1 = M1[t * 2], B2v = M2[t * 2];
    int I1 = MI[t * 2];
    const float y1 = M1[t * 2 + 1], y2 = M2[t * 2 + 1];
    const int yi = MI[t * 2 + 1];
    if (y1 < B1 || (y1 == B1 && yi < I1)) { B2v = fminf(B1, y2); B1 = y1; I1 = yi; }
    else B2v = fminf(B2v, y1);
    const int row = row0 + t;
    best_idx[row] = I1;
    if (B2v - B1 < MARGIN) {
      const int pos = atomicAdd(rcount, 1);
      rrows[pos] = row;
    }
  }
}

// ---------------- kernel 4: exact fp64 recheck, coalesced (wave-per-code) ----------------
__global__ void phase2_k(const float* __restrict__ z, const float* __restrict__ emb,
                         const double* __restrict__ e2_64, const double* __restrict__ inv64,
                         const int* __restrict__ rcount, const int* __restrict__ rrows,
                         int* __restrict__ best_idx) {
  __shared__ double zn[ND];
  __shared__ double RB[4];
  __shared__ int RI[4];
  const int t = threadIdx.x;
  const int w = t >> 6, l = t & 63;
  int cnt = rcount[0];
  if (cnt > NROWS) cnt = NROWS;
  for (int e = blockIdx.x; e < cnt; e += gridDim.x) {
    const int row = rrows[e];
    __syncthreads();
    zn[t] = (double)z[(size_t)row * ND + t] * inv64[row];
    __syncthreads();
    const double z0 = zn[l * 4], z1 = zn[l * 4 + 1], z2 = zn[l * 4 + 2], z3 = zn[l * 4 + 3];
    double B1 = 1e300;
    int I1 = 0;
    for (int c = w; c < NK; c += 4) {
      const float4 ev = *reinterpret_cast<const float4*>(emb + (size_t)c * ND + l * 4);
      double d = z0 * ev.x + z1 * ev.y + z2 * ev.z + z3 * ev.w;
      #pragma unroll
      for (int m = 32; m; m >>= 1) d += __shfl_xor(d, m, 64);
      const double s = e2_64[c] - 2.0 * d;
      if (s < B1) { B1 = s; I1 = c; }
    }
    if (l == 0) { RB[w] = B1; RI[w] = I1; }
    __syncthreads();
    if (t == 0) {
      double bb = RB[0]; int bi = RI[0];
      #pragma unroll
      for (int k = 1; k < 4; ++k)
        if (RB[k] < bb || (RB[k] == bb && RI[k] < bi)) { bb = RB[k]; bi = RI[k]; }
      best_idx[row] = bi;
    }
  }
}

// ---------------- kernel 5: gather z_q, loss partials, histogram, index output ----------------
__global__ void gather_k(const float* __restrict__ z, const float* __restrict__ emb,
                         const int* __restrict__ best_idx, const double* __restrict__ inv64,
                         float* __restrict__ out, double* __restrict__ partials,
                         int* __restrict__ counts) {
  __shared__ double wsum[4];
  const int w = threadIdx.x >> 6, lane = threadIdx.x & 63;
  const int row = blockIdx.x * 4 + w;
  const int idx = best_idx[row];
  const double inv = inv64[row];
  const float4 zv = *reinterpret_cast<const float4*>(z + (size_t)row * ND + lane * 4);
  const float4 ev = *reinterpret_cast<const float4*>(emb + (size_t)idx * ND + lane * 4);
  *reinterpret_cast<float4*>(out + (size_t)row * ND + lane * 4) = ev;  // z_q_st == z_q
  const double dx = (double)ev.x - (double)zv.x * inv;
  const double dy = (double)ev.y - (double)zv.y * inv;
  const double dz = (double)ev.z - (double)zv.z * inv;
  const double dw = (double)ev.w - (double)zv.w * inv;
  double s = dx * dx + dy * dy + dz * dz + dw * dw;
  #pragma unroll
  for (int m = 32; m; m >>= 1) s += __shfl_xor(s, m, 64);
  if (lane == 0) {
    wsum[w] = s;
    atomicAdd(&counts[idx], 1);
    out[IDX_OFF + row] = (float)idx;
  }
  __syncthreads();
  if (threadIdx.x == 0) partials[blockIdx.x] = wsum[0] + wsum[1] + wsum[2] + wsum[3];
}

// ---------------- kernel 6: scalars (losses + perplexity) ----------------
__global__ void finalize_k(const double* __restrict__ partials, const int* __restrict__ counts,
                           float* __restrict__ out) {
  __shared__ double red[256];
  const int t = threadIdx.x;
  double s = 0.0;
  for (int k = 0; k < 64; ++k) s += partials[t + 256 * k];
  red[t] = s;
  __syncthreads();
  for (int off = 128; off; off >>= 1) {
    if (t < off) red[t] += red[t + off];
    __syncthreads();
  }
  const double c = red[0] / (double)M_OUT;  // codebook_loss == commitment_loss
  __syncthreads();
  double h = 0.0;
  for (int k = 0; k < 16; ++k) {
    const double p = (double)counts[t * 16 + k] * (1.0 / 65536.0);
    h += p * log(p + 1e-10);
  }
  red[t] = h;
  __syncthreads();
  for (int off = 128; off; off >>= 1) {
    if (t < off) red[t] += red[t + off];
    __syncthreads();
  }
  if (t == 0) {
    const double perp = exp(-red[0]);
    out[M_OUT + 0] = (float)(c + 0.25 * c);  // vq_loss
    out[M_OUT + 1] = (float)c;               // codebook_loss
    out[M_OUT + 2] = (float)c;               // commitment_loss
    out[M_OUT + 3] = (float)perp;            // perplexity
  }
}

extern "C" void kernel_launch(void* const* d_in, const int* in_sizes, int n_in,
                              void* d_out, int out_size, void* d_ws, size_t ws_size,
                              hipStream_t stream) {
  const float* z = (const float*)d_in[0];
  const float* emb = (const float*)d_in[1];
  float* out = (float*)d_out;
  char* ws = (char*)d_ws;
  double* inv64   = (double*)(ws + WS_INV64);
  float*  e2_32   = (float*)(ws + WS_E2_32);
  double* e2_64   = (double*)(ws + WS_E2_64);
  unsigned short* ehi = (unsigned short*)(ws + WS_EHI);
  unsigned short* elo = (unsigned short*)(ws + WS_ELO);
  int*    best_i  = (int*)(ws + WS_BESTIDX);
  int*    counts  = (int*)(ws + WS_COUNTS);
  int*    rcount  = (int*)(ws + WS_RCOUNT);
  int*    rrows   = (int*)(ws + WS_RROWS);
  double* partials = (double*)(ws + WS_PART);
  // z hi/lo planes live in d_out[0..16M floats) -- fully overwritten by gather_k later
  unsigned short* zhi = (unsigned short*)d_out;  // [65536][256]
  unsigned short* zlo = zhi + M_OUT;             // [65536][256]

  hipMemsetAsync(ws + WS_COUNTS, 0, 16 * 1024 + 16, stream);  // counts + rcount
  rownorm_k<<<NROWS / 4, 256, 0, stream>>>(z, inv64, zhi, zlo);
  embnorm_k<<<NK / 4, 256, 0, stream>>>(emb, e2_32, e2_64, ehi, elo);
  phase1_k<<<NROWS / 64, 256, 0, stream>>>(zhi, zlo, ehi, elo, e2_32, best_i, rcount, rrows);
  phase2_k<<<1024, 256, 0, stream>>>(z, emb, e2_64, inv64, rcount, rrows, best_i);
  gather_k<<<NROWS / 4, 256, 0, stream>>>(z, emb, best_i, inv64, out, partials, counts);
  finalize_k<<<1, 256, 0, stream>>>(partials, counts, out);
}